// Round 5
// baseline (552.657 us; speedup 1.0000x reference)
//
#include <hip/hip_runtime.h>
#include <hip/hip_bf16.h>

#define NB_  4096   // B_ = B*NW windows
#define NG_  49
#define NC_  128
#define NH_  4
#define DH_  32
#define NN_  50     // NG+1
#define NIMG 64
#define NT_  3136
#define NCHK 8      // chunk blocks per image (global path)
#define CROWS 392   // NT_/NCHK
#define SCALE_ 0.17677669529663687f

// workspace layout (u16 units unless noted)
// weight frags: fp = (h*3+ty)*8 + jt*4 + kt, ty in {q,k,v}; [fp][lane][hi8|lo8] u16
#define BM_OFF    98304      // combined bias+mask frags [wx][h][tile16][lane][4] bf16
// float-offset area
#define FBASE  573440
#define U_F    (FBASE)            // [img][4][128] u vectors
#define CST_F  (FBASE + 32768)    // [img][4]
#define WACC_F (FBASE + 33024)    // [img][4][128] w accumulators
#define SUM_F  (FBASE + 65792)    // [img][4] exp-sums
#define CNT_F  (FBASE + 66048)    // [img] int fan-in counters

typedef unsigned short u16;
typedef unsigned int   u32;
typedef __attribute__((ext_vector_type(8))) short bf16x8;   // 8 bf16 (4 VGPRs)
typedef __attribute__((ext_vector_type(4))) float f32x4;    // MFMA acc

__device__ __forceinline__ float b2f(u16 u) {
    union { u32 i; float f; } v; v.i = ((u32)u) << 16; return v.f;
}
__device__ __forceinline__ u16 f2b(float f) {
    union { float f; u32 i; } v; v.f = f;
    u32 x = v.i;
    return (u16)((x + 0x7fffu + ((x >> 16) & 1u)) >> 16);
}
__device__ __forceinline__ u32 pk2(float a, float b) {   // 2xf32 -> packed bf16x2 (RNE)
    union { __hip_bfloat162 h2; u32 u; } v;
    v.h2 = __float22bfloat162_rn(make_float2(a, b));
    return v.u;
}

// load+pack the 4 x row-fragments for one K-tile (transient 16 VGPRs)
__device__ __forceinline__ void load_xf(const float* __restrict__ xbase,
                                        const float* __restrict__ xavgp,
                                        int kt, int l15, int g, bf16x8* xf)
{
    #pragma unroll
    for (int rt = 0; rt < 4; ++rt) {
        const int row = 16 * rt + l15;
        const float* rp = (row < NG_) ? (xbase + (size_t)row * NC_) : xavgp;
        const bool vld = (row <= NG_);
        float4 u0 = *(const float4*)(rp + 32 * kt + 8 * g);
        float4 u1 = *(const float4*)(rp + 32 * kt + 8 * g + 4);
        union { u32 w[4]; bf16x8 v; } F;
        F.w[0] = vld ? pk2(u0.x, u0.y) : 0u;
        F.w[1] = vld ? pk2(u0.z, u0.w) : 0u;
        F.w[2] = vld ? pk2(u1.x, u1.y) : 0u;
        F.w[3] = vld ? pk2(u1.z, u1.w) : 0u;
        xf[rt] = F.v;
    }
}

// ---------------- pre-pass: weight frags + bias+mask frags + per-image u/cst + zeroing ----------------
extern "C" __global__ __launch_bounds__(256)
void prep_kernel(const float* __restrict__ Wq, const float* __restrict__ Wkv,
                 const float* __restrict__ btab, const int* __restrict__ ridx,
                 const float* __restrict__ mask, const float* __restrict__ xavg,
                 const float* __restrict__ bq, const float* __restrict__ bkv,
                 u16* __restrict__ ws)
{
    __shared__ int   ridxS[NG_ * NN_];
    __shared__ float btabS[169 * NH_];
    __shared__ float xavgS[NC_];
    __shared__ float qaS[NC_];
    const int t = threadIdx.x, b = blockIdx.x;
    if (b < 24) {
        // transposed weight frags: lane holds out-col j (l15), 8 contiguous in-chans at 32kt+8g
        const int fp  = b * 4 + (t >> 6);
        const int lane = t & 63, l15 = lane & 15, g = lane >> 4;
        const int kt = fp & 3, rest = fp >> 2, jt = rest & 1, hty = rest >> 1;
        const int ty = hty % 3, hh = hty / 3;
        const int jc = 32 * hh + 16 * jt + l15;
        const float* src; int stride; float qs = 1.f;
        if (ty == 0)      { src = Wq  + jc;       stride = NC_;     qs = SCALE_; }
        else if (ty == 1) { src = Wkv + jc;       stride = 2 * NC_; }
        else              { src = Wkv + NC_ + jc; stride = 2 * NC_; }
        const int c0 = 32 * kt + 8 * g;
        u32 hi[4], lo[4];
        #pragma unroll
        for (int p = 0; p < 4; ++p) {
            const int c = c0 + 2 * p;
            float w0 = src[(size_t)c * stride] * qs;
            float w1 = src[(size_t)(c + 1) * stride] * qs;
            u16 h0 = f2b(w0), h1 = f2b(w1);
            hi[p] = (u32)h0 | ((u32)h1 << 16);
            lo[p] = (u32)f2b(w0 - b2f(h0)) | ((u32)f2b(w1 - b2f(h1)) << 16);
        }
        const size_t fo = ((size_t)fp * 64 + lane) * 16;   // interleaved hi|lo, 32 B/lane
        *(uint4*)(ws + fo)     = make_uint4(hi[0], hi[1], hi[2], hi[3]);
        *(uint4*)(ws + fo + 8) = make_uint4(lo[0], lo[1], lo[2], lo[3]);
    } else if (b < 88) {
        // bias+mask frags, one block per wx, in exact attention-load order
        const int wx = b - 24;
        for (int i = t; i < NG_ * NN_; i += 256) ridxS[i] = ridx[i];
        for (int i = t; i < 169 * NH_; i += 256) btabS[i] = btab[i];
        __syncthreads();
        for (int i = t; i < NH_ * 16 * 64; i += 256) {
            const int lane = i & 63, tile = (i >> 6) & 15, h = i >> 10;
            const int n  = 16 * (tile >> 2) + (lane & 15);   // q row
            const int m0 = 16 * (tile & 3) + 4 * (lane >> 4);// k col base
            u16 vv[4];
            #pragma unroll
            for (int e = 0; e < 4; ++e) {
                const int m = m0 + e;
                float val = -1e30f;
                if (n < NG_ && m < NN_)
                    val = btabS[ridxS[n * NN_ + m] * NH_ + h] + mask[((size_t)wx * NG_ + n) * NN_ + m];
                vv[e] = f2b(val);
            }
            u32* dst = (u32*)(ws + BM_OFF + ((size_t)((wx * NH_ + h) * 16 + tile) * 64 + lane) * 4);
            dst[0] = (u32)vv[0] | ((u32)vv[1] << 16);
            dst[1] = (u32)vv[2] | ((u32)vv[3] << 16);
        }
    } else {
        // per-image: qa -> u, cst; zero w/sum/cnt accumulators
        const int img = b - 88;
        float* wsF = (float*)ws;
        if (t < NC_) xavgS[t] = xavg[img * NC_ + t];
        __syncthreads();
        if (t < NC_) {
            float acc = bq[t];
            for (int c = 0; c < NC_; ++c) acc += xavgS[c] * Wq[c * NC_ + t];
            qaS[t] = acc;
        }
        __syncthreads();
        if (t < NC_) {
            const int c = t;
            const float* wr = Wkv + (size_t)c * 256;
            #pragma unroll
            for (int h = 0; h < NH_; ++h) {
                float acc = 0.f;
                #pragma unroll
                for (int j = 0; j < 32; ++j) acc += wr[h * 32 + j] * qaS[h * 32 + j];
                wsF[U_F + img * 512 + h * 128 + c] = acc;
            }
            #pragma unroll
            for (int h = 0; h < NH_; ++h) wsF[WACC_F + img * 512 + h * 128 + t] = 0.f;
        } else if (t < NC_ + NH_) {
            const int h = t - NC_;
            float acc = 0.f;
            for (int j = 0; j < 32; ++j) acc += qaS[h * 32 + j] * bkv[h * 32 + j];
            wsF[CST_F + img * 4 + h] = acc;
            wsF[SUM_F + img * 4 + h] = 0.f;
        } else if (t == NC_ + NH_) {
            ((int*)wsF)[CNT_F + img] = 0;
        }
    }
}

// ---------------- main kernel ----------------
struct ChunkShared {            // ~8.2 KiB (window path uses NO LDS)
    float waccS[4][4][128];     // [wave][h][c]
    float esumS[4][4];
    float sumS[4];
    int   flagS;
};

extern "C" __global__ __launch_bounds__(256, 4)
void wa2_kernel(const float* __restrict__ x, const float* __restrict__ xtotal,
                const float* __restrict__ xavg,
                const float* __restrict__ Wq, const float* __restrict__ bq,
                const float* __restrict__ Wkv, const float* __restrict__ bkv,
                float* __restrict__ out, u16* __restrict__ ws)
{
    __shared__ ChunkShared smc;
    const int t = threadIdx.x;
    const int blk = blockIdx.x;
    const int lane = t & 63, wv = t >> 6;

    if (blk >= NIMG * NCHK) {
        // =========== window path: per-wave, LDS-free, barrier-free, 2-sweep ===========
        const int wb   = blk - NIMG * NCHK;
        const int img  = wb >> 6;
        const int widx = wb & 63;
        const int h = wv, l15 = lane & 15, g = lane >> 4;
        const float* xbase = x + (size_t)wb * (NG_ * NC_);
        const float* xavgp = xavg + (size_t)img * NC_;

        // ---- S1: q,k projection (per-kt transient xf; accs 64 regs) ----
        bf16x8 qf[4], kf[4];
        {
            f32x4 aq[2][4], ak[2][4];
            #pragma unroll
            for (int jt = 0; jt < 2; ++jt) {
                f32x4 cq, ck;
                #pragma unroll
                for (int r = 0; r < 4; ++r) {
                    const int j = 32 * h + 16 * jt + 4 * g + r;
                    cq[r] = bq[j] * SCALE_;
                    ck[r] = bkv[j];
                }
                #pragma unroll
                for (int rt = 0; rt < 4; ++rt) { aq[jt][rt] = cq; ak[jt][rt] = ck; }
            }
            #pragma unroll
            for (int kt = 0; kt < 4; ++kt) {
                bf16x8 xf[4];
                load_xf(xbase, xavgp, kt, l15, g, xf);
                const u16* wq0 = ws + ((size_t)((h * 3 + 0) * 8 + kt) * 64 + lane) * 16;
                const u16* wk0 = ws + ((size_t)((h * 3 + 1) * 8 + kt) * 64 + lane) * 16;
                const bf16x8 qh0 = *(const bf16x8*)(wq0);
                const bf16x8 ql0 = *(const bf16x8*)(wq0 + 8);
                const bf16x8 qh1 = *(const bf16x8*)(wq0 + 64 * 64);   // jt=1: +4 frags = 4*64*16
                const bf16x8 ql1 = *(const bf16x8*)(wq0 + 64 * 64 + 8);
                const bf16x8 kh0 = *(const bf16x8*)(wk0);
                const bf16x8 kl0 = *(const bf16x8*)(wk0 + 8);
                const bf16x8 kh1 = *(const bf16x8*)(wk0 + 64 * 64);
                const bf16x8 kl1 = *(const bf16x8*)(wk0 + 64 * 64 + 8);
                #pragma unroll
                for (int rt = 0; rt < 4; ++rt) {
                    aq[0][rt] = __builtin_amdgcn_mfma_f32_16x16x32_bf16(qh0, xf[rt], aq[0][rt], 0, 0, 0);
                    aq[0][rt] = __builtin_amdgcn_mfma_f32_16x16x32_bf16(ql0, xf[rt], aq[0][rt], 0, 0, 0);
                    aq[1][rt] = __builtin_amdgcn_mfma_f32_16x16x32_bf16(qh1, xf[rt], aq[1][rt], 0, 0, 0);
                    aq[1][rt] = __builtin_amdgcn_mfma_f32_16x16x32_bf16(ql1, xf[rt], aq[1][rt], 0, 0, 0);
                    ak[0][rt] = __builtin_amdgcn_mfma_f32_16x16x32_bf16(kh0, xf[rt], ak[0][rt], 0, 0, 0);
                    ak[0][rt] = __builtin_amdgcn_mfma_f32_16x16x32_bf16(kl0, xf[rt], ak[0][rt], 0, 0, 0);
                    ak[1][rt] = __builtin_amdgcn_mfma_f32_16x16x32_bf16(kh1, xf[rt], ak[1][rt], 0, 0, 0);
                    ak[1][rt] = __builtin_amdgcn_mfma_f32_16x16x32_bf16(kl1, xf[rt], ak[1][rt], 0, 0, 0);
                }
            }
            // pack per row-tile: frag slot s=jt*4+r <-> chan 16jt+4g+r (shared sigma)
            #pragma unroll
            for (int rt = 0; rt < 4; ++rt) {
                union { u32 w[4]; bf16x8 v; } FQ, FK;
                FQ.w[0] = pk2(aq[0][rt][0], aq[0][rt][1]);
                FQ.w[1] = pk2(aq[0][rt][2], aq[0][rt][3]);
                FQ.w[2] = pk2(aq[1][rt][0], aq[1][rt][1]);
                FQ.w[3] = pk2(aq[1][rt][2], aq[1][rt][3]);
                FK.w[0] = pk2(ak[0][rt][0], ak[0][rt][1]);
                FK.w[1] = pk2(ak[0][rt][2], ak[0][rt][3]);
                FK.w[2] = pk2(ak[1][rt][0], ak[1][rt][1]);
                FK.w[3] = pk2(ak[1][rt][2], ak[1][rt][3]);
                qf[rt] = FQ.v; kf[rt] = FK.v;
            }
        }

        // ---- S2: v projection (xf reload is L1/L2-hot; accs 32 regs) ----
        bf16x8 vbf[2][2];
        {
            f32x4 av[4][2];
            #pragma unroll
            for (int tn = 0; tn < 2; ++tn) {
                const float bv = bkv[NC_ + 32 * h + 16 * tn + l15];
                #pragma unroll
                for (int tm = 0; tm < 4; ++tm) av[tm][tn] = (f32x4){bv, bv, bv, bv};
            }
            #pragma unroll
            for (int kt = 0; kt < 4; ++kt) {
                bf16x8 xf[4];
                load_xf(xbase, xavgp, kt, l15, g, xf);
                const u16* wv0 = ws + ((size_t)((h * 3 + 2) * 8 + kt) * 64 + lane) * 16;
                const bf16x8 vh0 = *(const bf16x8*)(wv0);
                const bf16x8 vl0 = *(const bf16x8*)(wv0 + 8);
                const bf16x8 vh1 = *(const bf16x8*)(wv0 + 64 * 64);
                const bf16x8 vl1 = *(const bf16x8*)(wv0 + 64 * 64 + 8);
                #pragma unroll
                for (int tm = 0; tm < 4; ++tm) {
                    av[tm][0] = __builtin_amdgcn_mfma_f32_16x16x32_bf16(xf[tm], vh0, av[tm][0], 0, 0, 0);
                    av[tm][0] = __builtin_amdgcn_mfma_f32_16x16x32_bf16(xf[tm], vl0, av[tm][0], 0, 0, 0);
                    av[tm][1] = __builtin_amdgcn_mfma_f32_16x16x32_bf16(xf[tm], vh1, av[tm][1], 0, 0, 0);
                    av[tm][1] = __builtin_amdgcn_mfma_f32_16x16x32_bf16(xf[tm], vl1, av[tm][1], 0, 0, 0);
                }
            }
            // pack PV B-frags: slot s <-> krow 32kt2+16(s>>2)+4g+(s&3) (shared tau with pa)
            #pragma unroll
            for (int kt2 = 0; kt2 < 2; ++kt2)
                #pragma unroll
                for (int tn = 0; tn < 2; ++tn) {
                    union { u32 w[4]; bf16x8 v; } F;
                    F.w[0] = pk2(av[2 * kt2][tn][0], av[2 * kt2][tn][1]);
                    F.w[1] = pk2(av[2 * kt2][tn][2], av[2 * kt2][tn][3]);
                    F.w[2] = pk2(av[2 * kt2 + 1][tn][0], av[2 * kt2 + 1][tn][1]);
                    F.w[3] = pk2(av[2 * kt2 + 1][tn][2], av[2 * kt2 + 1][tn][3]);
                    vbf[kt2][tn] = F.v;
                }
        }

        // ---- attention, fused per q-tile: QK^T (bm as C) -> no-max softmax -> PV -> store ----
        const u16* bmb = ws + BM_OFF + (size_t)(widx * NH_ + h) * 4096;
        #pragma unroll
        for (int tq = 0; tq < 4; ++tq) {
            f32x4 s[4];
            #pragma unroll
            for (int tk = 0; tk < 4; ++tk) {
                uint2 bm = *(const uint2*)(bmb + ((size_t)(tq * 4 + tk) * 64 + lane) * 4);
                f32x4 c0;
                c0[0] = b2f((u16)bm.x); c0[1] = b2f((u16)(bm.x >> 16));
                c0[2] = b2f((u16)bm.y); c0[3] = b2f((u16)(bm.y >> 16));
                s[tk] = __builtin_amdgcn_mfma_f32_16x16x32_bf16(kf[tk], qf[tq], c0, 0, 0, 0);
            }
            // no max-shift: window scores are O(+-10) << 87; pads exp(-1e30)=0
            float sum = 0.f;
            #pragma unroll
            for (int tk = 0; tk < 4; ++tk)
                #pragma unroll
                for (int r = 0; r < 4; ++r) {
                    float e = __expf(s[tk][r]);
                    s[tk][r] = e;
                    sum += e;
                }
            sum += __shfl_xor(sum, 16);
            sum += __shfl_xor(sum, 32);
            const float inv = 1.f / sum;

            bf16x8 pa[2];
            #pragma unroll
            for (int kt2 = 0; kt2 < 2; ++kt2) {
                union { u32 w[4]; bf16x8 v; } P;
                P.w[0] = pk2(s[2 * kt2][0] * inv, s[2 * kt2][1] * inv);
                P.w[1] = pk2(s[2 * kt2][2] * inv, s[2 * kt2][3] * inv);
                P.w[2] = pk2(s[2 * kt2 + 1][0] * inv, s[2 * kt2 + 1][1] * inv);
                P.w[3] = pk2(s[2 * kt2 + 1][2] * inv, s[2 * kt2 + 1][3] * inv);
                pa[kt2] = P.v;
            }
            #pragma unroll
            for (int tn = 0; tn < 2; ++tn) {
                f32x4 o = {0.f, 0.f, 0.f, 0.f};
                o = __builtin_amdgcn_mfma_f32_16x16x32_bf16(pa[0], vbf[0][tn], o, 0, 0, 0);
                o = __builtin_amdgcn_mfma_f32_16x16x32_bf16(pa[1], vbf[1][tn], o, 0, 0, 0);
                #pragma unroll
                for (int r = 0; r < 4; ++r) {
                    const int row = 16 * tq + 4 * g + r;
                    if (row < NG_)
                        out[(size_t)wb * (NG_ * NC_) + (size_t)row * NC_ + 32 * h + 16 * tn + l15] = o[r];
                }
            }
        }
    } else {
        // ======================= global path: chunked one-pass softmax-accumulate =======================
        ChunkShared& S = smc;
        float* wsF = (float*)ws;
        const int img = blk >> 3, ch = blk & 7;
        const int c0 = (lane & 31) * 4, roff = lane >> 5;

        // u, cst into registers (fixed c-slice per lane)
        float4 uR[NH_]; float cstR[NH_];
        #pragma unroll
        for (int h = 0; h < NH_; ++h) {
            uR[h]  = *(const float4*)&wsF[U_F + img * 512 + h * 128 + c0];
            cstR[h] = wsF[CST_F + img * 4 + h];
        }

        float wacc[NH_][4] = {};
        float esum[NH_] = {0.f, 0.f, 0.f, 0.f};
        const float* xb = xtotal + ((size_t)img * NT_ + ch * CROWS) * NC_;
        for (int it = 0; it < CROWS / 8; ++it) {
            const int m = it * 8 + wv * 2 + roff;
            float4 xv = *(const float4*)&xb[(size_t)m * NC_ + c0];
            float s[NH_];
            #pragma unroll
            for (int h = 0; h < NH_; ++h)
                s[h] = xv.x * uR[h].x + xv.y * uR[h].y + xv.z * uR[h].z + xv.w * uR[h].w;
            #pragma unroll
            for (int off = 1; off < 32; off <<= 1) {
                #pragma unroll
                for (int h = 0; h < NH_; ++h) s[h] += __shfl_xor(s[h], off);
            }
            #pragma unroll
            for (int h = 0; h < NH_; ++h) {
                const float e = __expf(s[h] + cstR[h]);   // no max-shift: |s| <~ 35 << 87
                wacc[h][0] += e * xv.x; wacc[h][1] += e * xv.y;
                wacc[h][2] += e * xv.z; wacc[h][3] += e * xv.w;
                if ((lane & 31) == 0) esum[h] += e;
            }
        }

        // combine row-halves (lane ^ 32 shares the same c-slice)
        #pragma unroll
        for (int h = 0; h < NH_; ++h) {
            #pragma unroll
            for (int i = 0; i < 4; ++i) wacc[h][i] += __shfl_xor(wacc[h][i], 32);
            esum[h] += __shfl_xor(esum[h], 32);
        }
        if (lane < 32) {
            #pragma unroll
            for (int h = 0; h < NH_; ++h)
                #pragma unroll
                for (int i = 0; i < 4; ++i) S.waccS[wv][h][c0 + i] = wacc[h][i];
            if (lane == 0) {
                #pragma unroll
                for (int h = 0; h < NH_; ++h) S.esumS[wv][h] = esum[h];
            }
        }
        __syncthreads();
        if (t < NC_) {
            #pragma unroll
            for (int h = 0; h < NH_; ++h) {
                float v = S.waccS[0][h][t] + S.waccS[1][h][t] + S.waccS[2][h][t] + S.waccS[3][h][t];
                atomicAdd(&wsF[WACC_F + img * 512 + h * 128 + t], v);
            }
        } else if (t < NC_ + NH_) {
            const int h = t - NC_;
            atomicAdd(&wsF[SUM_F + img * 4 + h],
                      S.esumS[0][h] + S.esumS[1][h] + S.esumS[2][h] + S.esumS[3][h]);
        }
        __threadfence();
        __syncthreads();
        if (t == 0) S.flagS = atomicAdd(&((int*)wsF)[CNT_F + img], 1);
        __syncthreads();
        if (S.flagS == NCHK - 1) {
            // last chunk of this image: finish out_avg = (w/sum)@Wv + bv
            float* wS = &S.waccS[0][0][0];      // reuse (all waves past barrier)
            for (int i = t; i < 512; i += 256)
                wS[i] = atomicAdd(&wsF[WACC_F + img * 512 + i], 0.f);
            if (t < NH_) S.sumS[t] = atomicAdd(&wsF[SUM_F + img * 4 + t], 0.f);
            __syncthreads();
            if (t < NC_) {
                const int h = t >> 5;
                const float inv = 1.f / S.sumS[h];
                float acc = bkv[NC_ + t];
                for (int c = 0; c < NC_; ++c)
                    acc += (wS[h * 128 + c] * inv) * Wkv[(size_t)c * 256 + NC_ + t];
                out[(size_t)NB_ * (NG_ * NC_) + img * NC_ + t] = acc;
            }
        }
    }
}

extern "C" void kernel_launch(void* const* d_in, const int* in_sizes, int n_in,
                              void* d_out, int out_size, void* d_ws, size_t ws_size,
                              hipStream_t stream) {
    const float* x      = (const float*)d_in[0];
    const float* xtotal = (const float*)d_in[1];
    const float* xavg   = (const float*)d_in[2];
    const float* mask   = (const float*)d_in[3];
    const float* Wq     = (const float*)d_in[4];
    const float* bq     = (const float*)d_in[5];
    const float* Wkv    = (const float*)d_in[6];
    const float* bkv    = (const float*)d_in[7];
    const float* btab   = (const float*)d_in[8];
    const int*   ridx   = (const int*)d_in[9];
    float* outp = (float*)d_out;
    u16*   ws   = (u16*)d_ws;
    (void)in_sizes; (void)n_in; (void)out_size; (void)ws_size;

    // prep: 24 weight-frag + 64 bias+mask + 64 per-image (u/cst + accumulator zeroing)
    prep_kernel<<<152, 256, 0, stream>>>(Wq, Wkv, btab, ridx, mask, xavg, bq, bkv, ws);
    // chunk blocks first (they feed the fan-in epilogue), then 4096 window blocks
    wa2_kernel<<<NIMG * NCHK + NB_, 256, 0, stream>>>(x, xtotal, xavg, Wq, bq,
                                                      Wkv, bkv, outp, ws);
}